// Round 6
// baseline (230.436 us; speedup 1.0000x reference)
//
#include <hip/hip_runtime.h>
#include <hip/hip_bf16.h>
#include <math.h>

typedef unsigned short u16;
typedef __bf16 v8bf __attribute__((ext_vector_type(8)));
typedef float f32x4 __attribute__((ext_vector_type(4)));
typedef float f32x16 __attribute__((ext_vector_type(16)));

// ---------- bf16 helpers ----------
__device__ __forceinline__ float us2f(u16 h) {
    union { unsigned int u; float f; } v; v.u = ((unsigned int)h) << 16; return v.f;
}
__device__ __forceinline__ u16 f2us(float f) {
    union { float f; unsigned int u; } v; v.f = f;
    unsigned int r = v.u + 0x7fffu + ((v.u >> 16) & 1u);   // RNE
    return (u16)(r >> 16);
}
__device__ __forceinline__ float gelu_f(float x) {
    return 0.5f * x * (1.0f + erff(x * 0.70710678118654752f));
}
__device__ __forceinline__ void gload_lds16(const u16* g, u16* l) {
    auto gp = reinterpret_cast<const __attribute__((address_space(1))) unsigned int*>(
        (uintptr_t)g);
    auto lp = reinterpret_cast<__attribute__((address_space(3))) unsigned int*>(
        (uintptr_t)l);
    __builtin_amdgcn_global_load_lds(gp, lp, 16, 0, 0);
}

// ---------- fused prep: cvt Wenc, cvt Wdec, Bbar/C2 ----------
__global__ __launch_bounds__(256) void prepall_kernel(
    const float* __restrict__ Wenc, u16* __restrict__ WeB,
    const float* __restrict__ Wdec, u16* __restrict__ WdB,
    const float* __restrict__ Lre, const float* __restrict__ Lim,
    const float* __restrict__ lstep,
    const float* __restrict__ Bre, const float* __restrict__ Bim,
    const float* __restrict__ Cre, const float* __restrict__ Cim,
    u16* __restrict__ Bbar, u16* __restrict__ C2)
{
    const int b = blockIdx.x, tid = threadIdx.x;
    if (b < 3072) {
        const float* in = (b < 2048) ? Wenc : Wdec;
        u16* outp = (b < 2048) ? WeB : WdB;
        const int i = (b < 2048 ? b : b - 2048) * 2048 + tid * 8;
        float4 a = *reinterpret_cast<const float4*>(in + i);
        float4 c = *reinterpret_cast<const float4*>(in + i + 4);
        u16 o[8] = { f2us(a.x), f2us(a.y), f2us(a.z), f2us(a.w),
                     f2us(c.x), f2us(c.y), f2us(c.z), f2us(c.w) };
        *reinterpret_cast<uint4*>(outp + i) = *reinterpret_cast<uint4*>(o);
        return;
    }
    const int idx = (b - 3072) * 256 + tid;   // 0..131071
    if (idx < 65536) {
        const int p = idx >> 10, d = idx & 1023;
        const float lr = Lre[p], li = Lim[p];
        const float dt = expf(lstep[p]);
        const float er = expf(lr * dt);
        const float ar = er * cosf(li * dt), ai = er * sinf(li * dt);
        const float nr = ar - 1.0f, ni = ai;
        const float den = lr * lr + li * li;
        const float cr = (nr * lr + ni * li) / den;
        const float ci = (ni * lr - nr * li) / den;
        const float br = Bre[idx], bi = Bim[idx];
        Bbar[p * 1024 + d]        = f2us(cr * br - ci * bi);
        Bbar[(64 + p) * 1024 + d] = f2us(cr * bi + ci * br);
    } else {
        const int i = idx - 65536;
        const int d = i >> 6, p = i & 63;
        C2[d * 128 + p]      = f2us( 2.0f * Cre[i]);
        C2[d * 128 + 64 + p] = f2us(-2.0f * Cim[i]);
    }
}

// ---------- LayerNorm ----------
template<typename TIN>
__global__ __launch_bounds__(256) void ln_kernel(const TIN* __restrict__ in,
                                                 const float* __restrict__ g,
                                                 const float* __restrict__ b,
                                                 u16* __restrict__ out)
{
    const int row = blockIdx.x, tid = threadIdx.x;
    const size_t base = (size_t)row * 1024 + tid * 4;
    float x0, x1, x2, x3;
    if constexpr (sizeof(TIN) == 4) {
        float4 v = *reinterpret_cast<const float4*>(in + base);
        x0 = v.x; x1 = v.y; x2 = v.z; x3 = v.w;
    } else {
        ushort4 v = *reinterpret_cast<const ushort4*>((const u16*)in + base);
        x0 = us2f(v.x); x1 = us2f(v.y); x2 = us2f(v.z); x3 = us2f(v.w);
    }
    float s = x0 + x1 + x2 + x3;
    float q = x0*x0 + x1*x1 + x2*x2 + x3*x3;
    #pragma unroll
    for (int o = 32; o; o >>= 1) { s += __shfl_down(s, o); q += __shfl_down(q, o); }
    __shared__ float red[8];
    if ((tid & 63) == 0) { red[tid >> 6] = s; red[4 + (tid >> 6)] = q; }
    __syncthreads();
    s = red[0] + red[1] + red[2] + red[3];
    q = red[4] + red[5] + red[6] + red[7];
    const float mu = s * (1.0f / 1024.0f);
    const float rs = rsqrtf(q * (1.0f / 1024.0f) - mu * mu + 1e-5f);
    float4 gv = *reinterpret_cast<const float4*>(g + tid * 4);
    float4 bv = *reinterpret_cast<const float4*>(b + tid * 4);
    ushort4 o4;
    o4.x = f2us((x0 - mu) * rs * gv.x + bv.x);
    o4.y = f2us((x1 - mu) * rs * gv.y + bv.y);
    o4.z = f2us((x2 - mu) * rs * gv.z + bv.z);
    o4.w = f2us((x3 - mu) * rs * gv.w + bv.w);
    *reinterpret_cast<ushort4*>(out + base) = o4;
}

// ---------- scan ----------
__global__ __launch_bounds__(256) void scan_kernel(
    const float* __restrict__ Bu,
    const float* __restrict__ Lre, const float* __restrict__ Lim,
    const float* __restrict__ lstep,
    u16* __restrict__ A2)
{
    const int b = blockIdx.x >> 6;
    const int p = blockIdx.x & 63;
    const int t = threadIdx.x;
    const float lr = Lre[p], li = Lim[p];
    const float dt = expf(lstep[p]);
    const float er = expf(lr * dt);
    const float ar = er * cosf(li * dt), ai = er * sinf(li * dt);

    const size_t base = ((size_t)b * 2048 + t * 8) * 128;
    float xr[8], xi[8];
    float sr = 0.f, si = 0.f;
    #pragma unroll
    for (int i = 0; i < 8; ++i) {
        const float br = Bu[base + i * 128 + p];
        const float bi = Bu[base + i * 128 + 64 + p];
        const float nr = ar * sr - ai * si + br;
        const float ni = ar * si + ai * sr + bi;
        sr = nr; si = ni;
        xr[i] = sr; xi[i] = si;
    }
    float fr = ar, fi = ai;
    #pragma unroll
    for (int s = 0; s < 3; ++s) { const float t2 = fr*fr - fi*fi; fi = 2.f*fr*fi; fr = t2; }
    __shared__ float Er[256], Ei[256];
    Er[t] = sr; Ei[t] = si;
    __syncthreads();
    float vr = sr, vi = si;
    for (int off = 1; off < 256; off <<= 1) {
        float pr = 0.f, pi = 0.f;
        if (t >= off) { pr = Er[t - off]; pi = Ei[t - off]; }
        __syncthreads();
        vr += fr * pr - fi * pi;
        vi += fr * pi + fi * pr;
        Er[t] = vr; Ei[t] = vi;
        const float nf = fr*fr - fi*fi; fi = 2.f*fr*fi; fr = nf;
        __syncthreads();
    }
    float cr = 0.f, ci = 0.f;
    if (t > 0) { cr = Er[t - 1]; ci = Ei[t - 1]; }
    float gr = ar * cr - ai * ci, gi = ar * ci + ai * cr;
    #pragma unroll
    for (int i = 0; i < 8; ++i) {
        xr[i] += gr; xi[i] += gi;
        const float n2 = ar * gr - ai * gi; gi = ar * gi + ai * gr; gr = n2;
    }
    #pragma unroll
    for (int i = 0; i < 8; ++i) {
        const size_t m = (size_t)b * 2048 + t * 8 + i;
        A2[m * 128 + p]      = f2us(xr[i]);
        A2[m * 128 + 64 + p] = f2us(xi[i]);
    }
}

// ---------- small MFMA GEMM (G1 Bu) ----------
template<int BM, int BN>
__global__ __launch_bounds__(64) void gemm_small_kernel(
    const u16* __restrict__ A, const u16* __restrict__ B, float* __restrict__ Cout,
    const int N, const int K)
{
    __shared__ u16 lsA[BM * 32];
    __shared__ u16 lsB[BN * 32];
    const int tid = threadIdx.x;
    const int lane = tid & 63;
    const int m0 = blockIdx.y * BM, n0 = blockIdx.x * BN;
    f32x4 acc[4][4] = {};
    for (int k0 = 0; k0 < K; k0 += 32) {
        #pragma unroll
        for (int j = 0; j < 4; ++j) {
            const int s = j * 64 + tid;
            gload_lds16(A + (size_t)(m0 + (s >> 2)) * K + k0 + (s & 3) * 8,
                        lsA + (s - lane) * 8);
            gload_lds16(B + (size_t)(n0 + (s >> 2)) * K + k0 + (s & 3) * 8,
                        lsB + (s - lane) * 8);
        }
        __syncthreads();
        v8bf af[4], bfv[4];
        #pragma unroll
        for (int f = 0; f < 4; ++f)
            af[f] = *reinterpret_cast<const v8bf*>(
                lsA + (f * 16 + (lane & 15)) * 32 + (lane >> 4) * 8);
        #pragma unroll
        for (int f = 0; f < 4; ++f)
            bfv[f] = *reinterpret_cast<const v8bf*>(
                lsB + (f * 16 + (lane & 15)) * 32 + (lane >> 4) * 8);
        #pragma unroll
        for (int fm = 0; fm < 4; ++fm)
            #pragma unroll
            for (int fn = 0; fn < 4; ++fn)
                acc[fm][fn] = __builtin_amdgcn_mfma_f32_16x16x32_bf16(
                    af[fm], bfv[fn], acc[fm][fn], 0, 0, 0);
        __syncthreads();
    }
    #pragma unroll
    for (int fm = 0; fm < 4; ++fm)
    #pragma unroll
    for (int fn = 0; fn < 4; ++fn)
    #pragma unroll
    for (int i = 0; i < 4; ++i) {
        const int r = m0 + fm * 16 + (lane >> 4) * 4 + i;
        const int c = n0 + fn * 16 + (lane & 15);
        Cout[(size_t)r * N + c] = acc[fm][fn][i];
    }
}

// ================= pipelined 256x128 GEMMs, 32x32x16 MFMA =================
// LDS tile: rows of 64 bf16 (128B); 16B slot s of row r at phys s^(r&7).
// One barrier per phase (end). Mandatory end-of-phase lgkmcnt(0) guarantees
// each wave's LDS reads drain before its barrier => stage@p vs reads@<=p-1 is
// race-free; every VMK precedes the barrier its consumers cross.
#define BARM()   asm volatile("s_barrier" ::: "memory")
#define LGKM0()  asm volatile("s_waitcnt lgkmcnt(0)" ::: "memory")
#define VMK(n)   asm volatile("s_waitcnt vmcnt(" #n ")" ::: "memory")
#define PRIO1    __builtin_amdgcn_s_setprio(1)
#define PRIO0    __builtin_amdgcn_s_setprio(0)
#define MMA32(acc, a, b) \
    acc = __builtin_amdgcn_mfma_f32_32x32x16_bf16(a, b, acc, 0, 0, 0)
// A frag: rows wm*128+mf*32+l31, k-slot kk*2+lh (xor-swizzled)
#define RDA(mf, kk) (*reinterpret_cast<const v8bf*>( \
    cb + ((wm) * 128 + (mf) * 32 + l31) * 64 + ((((kk) * 2 + lh) ^ l7) * 8)))
// B frag (GLU, ag = 0 a / 1 gate): rows 256+ag*128+wn*32+l31
#define RDBG(ag, kk) (*reinterpret_cast<const v8bf*>( \
    cb + (256 + (ag) * 128 + (wn) * 32 + l31) * 64 + ((((kk) * 2 + lh) ^ l7) * 8)))
// B frag (plain): rows 256+wn*32+l31
#define RDB4(kk) (*reinterpret_cast<const v8bf*>( \
    cb + (256 + (wn) * 32 + l31) * 64 + ((((kk) * 2 + lh) ^ l7) * 8)))
// stage one 128-row stream (2 gloads/thread), advance pointers
#define STAGE(s, bi) do { \
    u16* d0_ = lds + (bi) * BUFE + ((s) * 128 + (wid * 2 + 0) * 8) * 64; \
    u16* d1_ = lds + (bi) * BUFE + ((s) * 128 + (wid * 2 + 1) * 8) * 64; \
    gload_lds16(pS[s][0], d0_); gload_lds16(pS[s][1], d1_); \
    pS[s][0] += 64; pS[s][1] += 64; } while (0)

// ---------------- GEGLU kernel ----------------
#define GLU_HB(cb_, ab_, bb_, stA_, stB_) do { \
    const u16* cb = (cb_); \
    v8bf bfA[4], bfG[4], af[4]; \
    _Pragma("unroll") for (int mf = 0; mf < 4; ++mf) af[mf] = RDA(mf, 0); \
    _Pragma("unroll") for (int kk = 0; kk < 4; ++kk) { \
        bfA[kk] = RDBG(0, kk); bfG[kk] = RDBG(1, kk); } \
    if (stA_) STAGE(0, ab_); \
    PRIO1; \
    _Pragma("unroll") for (int mf = 0; mf < 4; ++mf) { \
        MMA32(accA[mf], af[mf], bfA[0]); MMA32(accG[mf], af[mf], bfG[0]); } \
    PRIO0; LGKM0(); BARM(); \
    _Pragma("unroll") for (int mf = 0; mf < 4; ++mf) af[mf] = RDA(mf, 1); \
    if (stA_) STAGE(1, ab_); \
    PRIO1; \
    _Pragma("unroll") for (int mf = 0; mf < 4; ++mf) { \
        MMA32(accA[mf], af[mf], bfA[1]); MMA32(accG[mf], af[mf], bfG[1]); } \
    PRIO0; LGKM0(); BARM(); \
    _Pragma("unroll") for (int mf = 0; mf < 4; ++mf) af[mf] = RDA(mf, 2); \
    if (stB_) STAGE(2, bb_); \
    PRIO1; \
    _Pragma("unroll") for (int mf = 0; mf < 4; ++mf) { \
        MMA32(accA[mf], af[mf], bfA[2]); MMA32(accG[mf], af[mf], bfG[2]); } \
    PRIO0; LGKM0(); BARM(); \
    _Pragma("unroll") for (int mf = 0; mf < 4; ++mf) af[mf] = RDA(mf, 3); \
    if (stB_) STAGE(3, bb_); \
    PRIO1; \
    _Pragma("unroll") for (int mf = 0; mf < 4; ++mf) { \
        MMA32(accA[mf], af[mf], bfA[3]); MMA32(accG[mf], af[mf], bfG[3]); } \
    PRIO0; LGKM0(); \
    if (stB_) { VMK(4); } else { VMK(0); } \
    BARM(); } while (0)

template<int NBX>
__global__ __launch_bounds__(512, 2) void geglu8p_kernel(
    const u16* __restrict__ A, const u16* __restrict__ Bm, u16* __restrict__ Cout,
    const int K, const int NO, const int NT)
{
    constexpr int BUFE = 512 * 64;
    __shared__ u16 lds[2 * BUFE];
    const int tid = threadIdx.x, lane = tid & 63, wid = tid >> 6;
    const int wm = wid >> 2, wn = wid & 3;
    const int l31 = lane & 31, lh = lane >> 5, l7 = lane & 7;
    const int bid = blockIdx.x;
    const int swz = (bid & 7) * (NBX * 4) + (bid >> 3);
    const int by = swz / NBX, bx = swz % NBX;
    const int m0 = by * 256, n0 = bx * 128;

    const int rl = lane >> 3;
    const int scol = ((lane & 7) ^ rl) * 8;
    const u16* pS[4][2];
    #pragma unroll
    for (int j = 0; j < 2; ++j) {
        const int rloc = (wid * 2 + j) * 8 + rl;
        pS[0][j] = A  + (size_t)(m0 + rloc)       * K + scol;
        pS[1][j] = A  + (size_t)(m0 + 128 + rloc) * K + scol;
        pS[2][j] = Bm + (size_t)(n0 + rloc)       * K + scol;
        pS[3][j] = Bm + (size_t)(NO + n0 + rloc)  * K + scol;
    }

    f32x16 accA[4] = {};
    f32x16 accG[4] = {};

    #pragma unroll
    for (int t = 0; t < 2; ++t) { STAGE(0, t); STAGE(1, t); STAGE(2, t); STAGE(3, t); }
    VMK(0);
    BARM();

    const int NI = NT >> 1;
    for (int i = 0; i < NI; ++i) {
        const bool s1 = (i > 0);
        const bool s2 = (2 * i + 2 < NT);
        const bool s3 = (2 * i + 3 < NT);
        GLU_HB(lds,        1, 0, s1, s2);
        GLU_HB(lds + BUFE, 0, 1, s2, s3);
    }

    #pragma unroll
    for (int mf = 0; mf < 4; ++mf)
    #pragma unroll
    for (int q = 0; q < 16; ++q) {
        const int r = m0 + wm * 128 + mf * 32 + (q & 3) + 8 * (q >> 2) + 4 * lh;
        const int c = n0 + wn * 32 + l31;
        Cout[(size_t)r * NO + c] = f2us(accA[mf][q] * gelu_f(accG[mf][q]));
    }
}

// ---------------- plain GEMM (EPI 1 / 3), 2 fat phases per K-tile ----------------
#define P4_HB(cb_, ab_, bb_, stA_, stB_) do { \
    const u16* cb = (cb_); \
    v8bf bfv[4], af0[4], af1[4]; \
    _Pragma("unroll") for (int mf = 0; mf < 4; ++mf) { \
        af0[mf] = RDA(mf, 0); af1[mf] = RDA(mf, 1); } \
    _Pragma("unroll") for (int kk = 0; kk < 4; ++kk) bfv[kk] = RDB4(kk); \
    if (stA_) { STAGE(0, ab_); STAGE(1, ab_); } \
    PRIO1; \
    _Pragma("unroll") for (int mf = 0; mf < 4; ++mf) { \
        MMA32(acc[mf], af0[mf], bfv[0]); MMA32(acc[mf], af1[mf], bfv[1]); } \
    PRIO0; LGKM0(); BARM(); \
    _Pragma("unroll") for (int mf = 0; mf < 4; ++mf) { \
        af0[mf] = RDA(mf, 2); af1[mf] = RDA(mf, 3); } \
    if (stB_) STAGE(2, bb_); \
    PRIO1; \
    _Pragma("unroll") for (int mf = 0; mf < 4; ++mf) { \
        MMA32(acc[mf], af0[mf], bfv[2]); MMA32(acc[mf], af1[mf], bfv[3]); } \
    PRIO0; LGKM0(); \
    if (stB_) { VMK(2); } else { VMK(0); } \
    BARM(); } while (0)

template<int EPI, int NBX>
__global__ __launch_bounds__(512, 2) void gemm4p_kernel(
    const u16* __restrict__ A, const u16* __restrict__ Bm, void* __restrict__ Cout,
    const int K, const int NO, const int NT,
    const u16* __restrict__ aux, const float* __restrict__ dskip)
{
    constexpr int BUFE = 384 * 64;
    __shared__ u16 lds[2 * BUFE];
    const int tid = threadIdx.x, lane = tid & 63, wid = tid >> 6;
    const int wm = wid >> 2, wn = wid & 3;
    const int l31 = lane & 31, lh = lane >> 5, l7 = lane & 7;
    const int bid = blockIdx.x;
    const int swz = (bid & 7) * (NBX * 4) + (bid >> 3);
    const int by = swz / NBX, bx = swz % NBX;
    const int m0 = by * 256, n0 = bx * 128;

    const int rl = lane >> 3;
    const int scol = ((lane & 7) ^ rl) * 8;
    const u16* pS[3][2];
    #pragma unroll
    for (int j = 0; j < 2; ++j) {
        const int rloc = (wid * 2 + j) * 8 + rl;
        pS[0][j] = A  + (size_t)(m0 + rloc)       * K + scol;
        pS[1][j] = A  + (size_t)(m0 + 128 + rloc) * K + scol;
        pS[2][j] = Bm + (size_t)(n0 + rloc)       * K + scol;
    }

    f32x16 acc[4] = {};

    #pragma unroll
    for (int t = 0; t < 2; ++t) { STAGE(0, t); STAGE(1, t); STAGE(2, t); }
    VMK(0);
    BARM();

    const int NI = NT >> 1;
    for (int i = 0; i < NI; ++i) {
        const bool s1 = (i > 0);
        const bool s2 = (2 * i + 2 < NT);
        const bool s3 = (2 * i + 3 < NT);
        P4_HB(lds,        1, 0, s1, s2);
        P4_HB(lds + BUFE, 0, 1, s2, s3);
    }

    #pragma unroll
    for (int mf = 0; mf < 4; ++mf)
    #pragma unroll
    for (int q = 0; q < 16; ++q) {
        const int r = m0 + wm * 128 + mf * 32 + (q & 3) + 8 * (q >> 2) + 4 * lh;
        const int c = n0 + wn * 32 + l31;
        const size_t o = (size_t)r * NO + c;
        const float v = acc[mf][q];
        if constexpr (EPI == 1) {
            const float u = us2f(aux[o]);
            const float t2 = v + dskip[c] * u;
            ((u16*)Cout)[o] = f2us(gelu_f(t2) + u);
        } else {
            ((float*)Cout)[o] = v + us2f(aux[o]);
        }
    }
}

// ---------- workspace layout (bytes) ----------
static constexpr size_t OFF_FX  = 0;                              // bf16 16.78MB
static constexpr size_t OFF_BU  = 16777216;                       // f32   4.19MB
static constexpr size_t OFF_A2  = 20971520;                       // bf16  2.10MB
static constexpr size_t OFF_E2  = 0;                              // bf16 33.55MB (alias)
static constexpr size_t OFF_FX2 = 33554432;                       // bf16 16.78MB
static constexpr size_t OFF_BB  = 50331648;                       // bf16  0.26MB
static constexpr size_t OFF_C2  = 50593792;                       // bf16  0.26MB
static constexpr size_t OFF_WE  = 50855936;                       // bf16  8.39MB
static constexpr size_t OFF_WD  = 59244544;                       // bf16  4.19MB

extern "C" void kernel_launch(void* const* d_in, const int* in_sizes, int n_in,
                              void* d_out, int out_size, void* d_ws, size_t ws_size,
                              hipStream_t stream) {
    const float* x    = (const float*)d_in[0];
    const float* l1g  = (const float*)d_in[1];
    const float* l1b  = (const float*)d_in[2];
    const float* l2g  = (const float*)d_in[3];
    const float* l2b  = (const float*)d_in[4];
    const float* Lre  = (const float*)d_in[5];
    const float* Lim  = (const float*)d_in[6];
    const float* Bre  = (const float*)d_in[7];
    const float* Bim  = (const float*)d_in[8];
    const float* Cre  = (const float*)d_in[9];
    const float* Cim  = (const float*)d_in[10];
    const float* Dsk  = (const float*)d_in[11];
    const float* lst  = (const float*)d_in[12];
    const float* Wenc = (const float*)d_in[13];
    const float* Wdec = (const float*)d_in[14];
    float* out = (float*)d_out;

    char* ws = (char*)d_ws;
    u16*   fx   = (u16*)(ws + OFF_FX);
    float* Bu   = (float*)(ws + OFF_BU);
    u16*   A2   = (u16*)(ws + OFF_A2);
    u16*   e2   = (u16*)(ws + OFF_E2);
    u16*   fx2  = (u16*)(ws + OFF_FX2);
    u16*   Bbar = (u16*)(ws + OFF_BB);
    u16*   C2   = (u16*)(ws + OFF_C2);
    u16*   WeB  = (u16*)(ws + OFF_WE);
    u16*   WdB  = (u16*)(ws + OFF_WD);
    u16*   h    = (u16*)d_out;           // h (bf16) in d_out's first half

    // 1) fx = LN1(x)
    ln_kernel<float><<<8192, 256, 0, stream>>>(x, l1g, l1b, fx);
    // 1b) weight conversions + B_bar / C2 precompute (fused)
    prepall_kernel<<<3584, 256, 0, stream>>>(Wenc, WeB, Wdec, WdB,
                                             Lre, Lim, lst, Bre, Bim, Cre, Cim,
                                             Bbar, C2);
    // 2) Bu = fx @ Bbar^T
    gemm_small_kernel<64, 64><<<dim3(2, 128), 64, 0, stream>>>(
        fx, Bbar, Bu, 128, 1024);
    // 3) scan -> A2
    scan_kernel<<<256, 256, 0, stream>>>(Bu, Lre, Lim, lst, A2);
    // 4) h = gelu(A2 @ C2^T + Dskip*fx) + fx
    gemm4p_kernel<1, 8><<<256, 512, 0, stream>>>(
        A2, C2, h, 128, 1024, 2, fx, Dsk);
    // 5) fx2 = LN2(h)
    ln_kernel<u16><<<8192, 256, 0, stream>>>(h, l2g, l2b, fx2);
    // 6) e2 = (fx2 @ We[:2048]^T) * gelu(fx2 @ We[2048:]^T)
    geglu8p_kernel<16><<<512, 512, 0, stream>>>(fx2, WeB, e2, 1024, 2048, 16);
    // 7) out = e2 @ WdB^T + fx2
    gemm4p_kernel<3, 8><<<256, 512, 0, stream>>>(
        e2, WdB, out, 2048, 1024, 32, fx2, nullptr);

    (void)in_sizes; (void)n_in; (void)out_size; (void)ws_size;
}

// Round 10
// 223.357 us; speedup vs baseline: 1.0317x; 1.0317x over previous
//
#include <hip/hip_runtime.h>
#include <hip/hip_bf16.h>
#include <math.h>

typedef unsigned short u16;
typedef __bf16 v8bf __attribute__((ext_vector_type(8)));
typedef float f32x4 __attribute__((ext_vector_type(4)));
typedef float f32x16 __attribute__((ext_vector_type(16)));

// ---------- bf16 helpers ----------
__device__ __forceinline__ float us2f(u16 h) {
    union { unsigned int u; float f; } v; v.u = ((unsigned int)h) << 16; return v.f;
}
__device__ __forceinline__ u16 f2us(float f) {
    union { float f; unsigned int u; } v; v.f = f;
    unsigned int r = v.u + 0x7fffu + ((v.u >> 16) & 1u);   // RNE
    return (u16)(r >> 16);
}
__device__ __forceinline__ float gelu_f(float x) {
    return 0.5f * x * (1.0f + erff(x * 0.70710678118654752f));
}
__device__ __forceinline__ void gload_lds16(const u16* g, u16* l) {
    auto gp = reinterpret_cast<const __attribute__((address_space(1))) unsigned int*>(
        (uintptr_t)g);
    auto lp = reinterpret_cast<__attribute__((address_space(3))) unsigned int*>(
        (uintptr_t)l);
    __builtin_amdgcn_global_load_lds(gp, lp, 16, 0, 0);
}

// ---------- fused prep ----------
__global__ __launch_bounds__(256) void prepall_kernel(
    const float* __restrict__ Wenc, u16* __restrict__ WeB,
    const float* __restrict__ Wdec, u16* __restrict__ WdB,
    const float* __restrict__ Lre, const float* __restrict__ Lim,
    const float* __restrict__ lstep,
    const float* __restrict__ Bre, const float* __restrict__ Bim,
    const float* __restrict__ Cre, const float* __restrict__ Cim,
    u16* __restrict__ Bbar, u16* __restrict__ C2)
{
    const int b = blockIdx.x, tid = threadIdx.x;
    if (b < 3072) {
        const float* in = (b < 2048) ? Wenc : Wdec;
        u16* outp = (b < 2048) ? WeB : WdB;
        const int i = (b < 2048 ? b : b - 2048) * 2048 + tid * 8;
        float4 a = *reinterpret_cast<const float4*>(in + i);
        float4 c = *reinterpret_cast<const float4*>(in + i + 4);
        u16 o[8] = { f2us(a.x), f2us(a.y), f2us(a.z), f2us(a.w),
                     f2us(c.x), f2us(c.y), f2us(c.z), f2us(c.w) };
        *reinterpret_cast<uint4*>(outp + i) = *reinterpret_cast<uint4*>(o);
        return;
    }
    const int idx = (b - 3072) * 256 + tid;
    if (idx < 65536) {
        const int p = idx >> 10, d = idx & 1023;
        const float lr = Lre[p], li = Lim[p];
        const float dt = expf(lstep[p]);
        const float er = expf(lr * dt);
        const float ar = er * cosf(li * dt), ai = er * sinf(li * dt);
        const float nr = ar - 1.0f, ni = ai;
        const float den = lr * lr + li * li;
        const float cr = (nr * lr + ni * li) / den;
        const float ci = (ni * lr - nr * li) / den;
        const float br = Bre[idx], bi = Bim[idx];
        Bbar[p * 1024 + d]        = f2us(cr * br - ci * bi);
        Bbar[(64 + p) * 1024 + d] = f2us(cr * bi + ci * br);
    } else {
        const int i = idx - 65536;
        const int d = i >> 6, p = i & 63;
        C2[d * 128 + p]      = f2us( 2.0f * Cre[i]);
        C2[d * 128 + 64 + p] = f2us(-2.0f * Cim[i]);
    }
}

// ---------- LayerNorm ----------
template<typename TIN>
__global__ __launch_bounds__(256) void ln_kernel(const TIN* __restrict__ in,
                                                 const float* __restrict__ g,
                                                 const float* __restrict__ b,
                                                 u16* __restrict__ out)
{
    const int row = blockIdx.x, tid = threadIdx.x;
    const size_t base = (size_t)row * 1024 + tid * 4;
    float x0, x1, x2, x3;
    if constexpr (sizeof(TIN) == 4) {
        float4 v = *reinterpret_cast<const float4*>(in + base);
        x0 = v.x; x1 = v.y; x2 = v.z; x3 = v.w;
    } else {
        ushort4 v = *reinterpret_cast<const ushort4*>((const u16*)in + base);
        x0 = us2f(v.x); x1 = us2f(v.y); x2 = us2f(v.z); x3 = us2f(v.w);
    }
    float s = x0 + x1 + x2 + x3;
    float q = x0*x0 + x1*x1 + x2*x2 + x3*x3;
    #pragma unroll
    for (int o = 32; o; o >>= 1) { s += __shfl_down(s, o); q += __shfl_down(q, o); }
    __shared__ float red[8];
    if ((tid & 63) == 0) { red[tid >> 6] = s; red[4 + (tid >> 6)] = q; }
    __syncthreads();
    s = red[0] + red[1] + red[2] + red[3];
    q = red[4] + red[5] + red[6] + red[7];
    const float mu = s * (1.0f / 1024.0f);
    const float rs = rsqrtf(q * (1.0f / 1024.0f) - mu * mu + 1e-5f);
    float4 gv = *reinterpret_cast<const float4*>(g + tid * 4);
    float4 bv = *reinterpret_cast<const float4*>(b + tid * 4);
    ushort4 o4;
    o4.x = f2us((x0 - mu) * rs * gv.x + bv.x);
    o4.y = f2us((x1 - mu) * rs * gv.y + bv.y);
    o4.z = f2us((x2 - mu) * rs * gv.z + bv.z);
    o4.w = f2us((x3 - mu) * rs * gv.w + bv.w);
    *reinterpret_cast<ushort4*>(out + base) = o4;
}

// ---------- scan ----------
__global__ __launch_bounds__(256) void scan_kernel(
    const float* __restrict__ Bu,
    const float* __restrict__ Lre, const float* __restrict__ Lim,
    const float* __restrict__ lstep,
    u16* __restrict__ A2)
{
    const int b = blockIdx.x >> 6;
    const int p = blockIdx.x & 63;
    const int t = threadIdx.x;
    const float lr = Lre[p], li = Lim[p];
    const float dt = expf(lstep[p]);
    const float er = expf(lr * dt);
    const float ar = er * cosf(li * dt), ai = er * sinf(li * dt);

    const size_t base = ((size_t)b * 2048 + t * 8) * 128;
    float xr[8], xi[8];
    float sr = 0.f, si = 0.f;
    #pragma unroll
    for (int i = 0; i < 8; ++i) {
        const float br = Bu[base + i * 128 + p];
        const float bi = Bu[base + i * 128 + 64 + p];
        const float nr = ar * sr - ai * si + br;
        const float ni = ar * si + ai * sr + bi;
        sr = nr; si = ni;
        xr[i] = sr; xi[i] = si;
    }
    float fr = ar, fi = ai;
    #pragma unroll
    for (int s = 0; s < 3; ++s) { const float t2 = fr*fr - fi*fi; fi = 2.f*fr*fi; fr = t2; }
    __shared__ float Er[256], Ei[256];
    Er[t] = sr; Ei[t] = si;
    __syncthreads();
    float vr = sr, vi = si;
    for (int off = 1; off < 256; off <<= 1) {
        float pr = 0.f, pi = 0.f;
        if (t >= off) { pr = Er[t - off]; pi = Ei[t - off]; }
        __syncthreads();
        vr += fr * pr - fi * pi;
        vi += fr * pi + fi * pr;
        Er[t] = vr; Ei[t] = vi;
        const float nf = fr*fr - fi*fi; fi = 2.f*fr*fi; fr = nf;
        __syncthreads();
    }
    float cr = 0.f, ci = 0.f;
    if (t > 0) { cr = Er[t - 1]; ci = Ei[t - 1]; }
    float gr = ar * cr - ai * ci, gi = ar * ci + ai * cr;
    #pragma unroll
    for (int i = 0; i < 8; ++i) {
        xr[i] += gr; xi[i] += gi;
        const float n2 = ar * gr - ai * gi; gi = ar * gi + ai * gr; gr = n2;
    }
    #pragma unroll
    for (int i = 0; i < 8; ++i) {
        const size_t m = (size_t)b * 2048 + t * 8 + i;
        A2[m * 128 + p]      = f2us(xr[i]);
        A2[m * 128 + 64 + p] = f2us(xi[i]);
    }
}

// ---------- small MFMA GEMM (G1 Bu) ----------
template<int BM, int BN>
__global__ __launch_bounds__(64) void gemm_small_kernel(
    const u16* __restrict__ A, const u16* __restrict__ B, float* __restrict__ Cout,
    const int N, const int K)
{
    __shared__ u16 lsA[BM * 32];
    __shared__ u16 lsB[BN * 32];
    const int tid = threadIdx.x;
    const int lane = tid & 63;
    const int m0 = blockIdx.y * BM, n0 = blockIdx.x * BN;
    f32x4 acc[4][4] = {};
    for (int k0 = 0; k0 < K; k0 += 32) {
        #pragma unroll
        for (int j = 0; j < 4; ++j) {
            const int s = j * 64 + tid;
            gload_lds16(A + (size_t)(m0 + (s >> 2)) * K + k0 + (s & 3) * 8,
                        lsA + (s - lane) * 8);
            gload_lds16(B + (size_t)(n0 + (s >> 2)) * K + k0 + (s & 3) * 8,
                        lsB + (s - lane) * 8);
        }
        __syncthreads();
        v8bf af[4], bfv[4];
        #pragma unroll
        for (int f = 0; f < 4; ++f)
            af[f] = *reinterpret_cast<const v8bf*>(
                lsA + (f * 16 + (lane & 15)) * 32 + (lane >> 4) * 8);
        #pragma unroll
        for (int f = 0; f < 4; ++f)
            bfv[f] = *reinterpret_cast<const v8bf*>(
                lsB + (f * 16 + (lane & 15)) * 32 + (lane >> 4) * 8);
        #pragma unroll
        for (int fm = 0; fm < 4; ++fm)
            #pragma unroll
            for (int fn = 0; fn < 4; ++fn)
                acc[fm][fn] = __builtin_amdgcn_mfma_f32_16x16x32_bf16(
                    af[fm], bfv[fn], acc[fm][fn], 0, 0, 0);
        __syncthreads();
    }
    #pragma unroll
    for (int fm = 0; fm < 4; ++fm)
    #pragma unroll
    for (int fn = 0; fn < 4; ++fn)
    #pragma unroll
    for (int i = 0; i < 4; ++i) {
        const int r = m0 + fm * 16 + (lane >> 4) * 4 + i;
        const int c = n0 + fn * 16 + (lane & 15);
        Cout[(size_t)r * N + c] = acc[fm][fn][i];
    }
}

// ================= pipelined GEMMs: round-6 sync skeleton + precomputed addrs =================
// Per phase: reads -> stage -> MFMA -> lgkmcnt(0) -> [vmcnt] -> ONE barrier.
#define BARM()   asm volatile("s_barrier" ::: "memory")
#define LGKM0()  asm volatile("s_waitcnt lgkmcnt(0)" ::: "memory")
#define VMK(n)   asm volatile("s_waitcnt vmcnt(" #n ")" ::: "memory")
#define PRIO1    __builtin_amdgcn_s_setprio(1)
#define PRIO0    __builtin_amdgcn_s_setprio(0)
#define MMA32(acc, a, b) \
    acc = __builtin_amdgcn_mfma_f32_32x32x16_bf16(a, b, acc, 0, 0, 0)

// ---------------- GEGLU: 256x128 tile, BK=64, 8 waves, LDS 128KB ----------------
// LDS u16 layout: A buf0 [0,16384) | A buf1 [16384,32768) | B buf0 [32768,49152)
// | B buf1 [49152,65536). B rows: 0-127 = a, 128-255 = gate.
#define G_RA(af, kk, BI) { _Pragma("unroll") \
    for (int mf = 0; mf < 4; ++mf) \
        af[mf] = *reinterpret_cast<const v8bf*>(pA[kk] + mf * 2048 + (BI) * 16384); }
#define G_RB(kk, ag, BI) \
    (*reinterpret_cast<const v8bf*>(pB[kk] + (ag) * 8192 + (BI) * 16384))
#define G_ST(s, bi) do { \
    const int db_ = (((s) & 2) ? 32768 : 0) + (bi) * 16384 + (((s) & 1) ? 8192 : 0); \
    gload_lds16(pS[s][0], lds + db_ + (wid * 2 + 0) * 512); \
    gload_lds16(pS[s][1], lds + db_ + (wid * 2 + 1) * 512); \
    pS[s][0] += 64; pS[s][1] += 64; } while (0)
#define G_MM(kk) { _Pragma("unroll") \
    for (int mf = 0; mf < 4; ++mf) { \
        MMA32(accA[mf], af[mf], bA[kk]); MMA32(accG[mf], af[mf], bG[kk]); } }
#define G_TILE(BI, stA_, stB_) do { \
    v8bf af[4], bA[4], bG[4]; \
    G_RA(af, 0, BI); \
    _Pragma("unroll") for (int kk = 0; kk < 4; ++kk) { \
        bA[kk] = G_RB(kk, 0, BI); bG[kk] = G_RB(kk, 1, BI); } \
    if (stA_) G_ST(0, (BI) ^ 1); \
    PRIO1; G_MM(0); PRIO0; LGKM0(); BARM(); \
    G_RA(af, 1, BI); \
    if (stA_) G_ST(1, (BI) ^ 1); \
    PRIO1; G_MM(1); PRIO0; LGKM0(); BARM(); \
    G_RA(af, 2, BI); \
    if (stB_) G_ST(2, BI); \
    PRIO1; G_MM(2); PRIO0; LGKM0(); BARM(); \
    G_RA(af, 3, BI); \
    if (stB_) G_ST(3, BI); \
    PRIO1; G_MM(3); PRIO0; LGKM0(); \
    if (stB_) { VMK(4); } else { VMK(0); } \
    BARM(); } while (0)

template<int NBX>
__global__ __launch_bounds__(512, 2) void geglu_kernel(
    const u16* __restrict__ A, const u16* __restrict__ Bm, u16* __restrict__ Cout,
    const int K, const int NO, const int NT)
{
    __shared__ u16 lds[65536];
    const int tid = threadIdx.x, lane = tid & 63, wid = tid >> 6;
    const int wm = wid >> 2, wn = wid & 3;
    const int l31 = lane & 31, lh = lane >> 5, l7 = lane & 7;
    const int bid = blockIdx.x;
    const int chunk = (int)gridDim.x >> 3;
    const int swz = (bid & 7) * chunk + (bid >> 3);
    const int by = swz / NBX, bx = swz % NBX;
    const int m0 = by * 256, n0 = bx * 128;

    const int rl = lane >> 3;
    const int scol = ((lane & 7) ^ rl) * 8;
    const u16* pS[4][2];
    #pragma unroll
    for (int j = 0; j < 2; ++j) {
        const int rloc = (wid * 2 + j) * 8 + rl;
        pS[0][j] = A  + (size_t)(m0 + rloc)       * K + scol;
        pS[1][j] = A  + (size_t)(m0 + 128 + rloc) * K + scol;
        pS[2][j] = Bm + (size_t)(n0 + rloc)       * K + scol;
        pS[3][j] = Bm + (size_t)(NO + n0 + rloc)  * K + scol;
    }
    const u16* pA[4];
    const u16* pB[4];
    #pragma unroll
    for (int kk = 0; kk < 4; ++kk) {
        const int phys = ((kk * 2 + lh) ^ l7) * 8;
        pA[kk] = lds + (wm * 128 + l31) * 64 + phys;
        pB[kk] = lds + 32768 + (wn * 32 + l31) * 64 + phys;
    }

    f32x16 accA[4] = {};
    f32x16 accG[4] = {};

    #pragma unroll
    for (int t = 0; t < 2; ++t) { G_ST(0, t); G_ST(1, t); G_ST(2, t); G_ST(3, t); }
    VMK(0);
    BARM();

    const int NI = NT >> 1;
    for (int i = 0; i < NI; ++i) {
        const bool s1 = (i > 0);
        const bool s2 = (2 * i + 2 < NT);
        const bool s3 = (2 * i + 3 < NT);
        G_TILE(0, s1, s2);
        G_TILE(1, s2, s3);
    }

    #pragma unroll
    for (int mf = 0; mf < 4; ++mf)
    #pragma unroll
    for (int q = 0; q < 16; ++q) {
        const int r = m0 + wm * 128 + mf * 32 + (q & 3) + 8 * (q >> 2) + 4 * lh;
        const int c = n0 + wn * 32 + l31;
        Cout[(size_t)r * NO + c] = f2us(accA[mf][q] * gelu_f(accG[mf][q]));
    }
}

// ---------------- plain GEMM: 128x128 tile, BK=64, 4 waves, LDS 64KB ----------------
// LDS u16: A buf0 [0,8192) | A buf1 [8192,16384) | B buf0 [16384,24576) | B buf1 [24576,32768)
// FIX (round 10): consume ALL FOUR K16-subtiles per BK=64 tile (rounds 7-9 only
// consumed kk=0,1 — half of K silently dropped; deterministic absmax 2.55).
// Phase 0: af kk0-1 + ALL B reads (B region is staged into during phase 1, so
// its reads must drain before the phase-0 barrier) + A-stage + 8 MFMA.
// Phase 1: af kk2-3 + B-stage + 8 MFMA + counted VMK.
#define Q_RA2(af, k0_, BI) { _Pragma("unroll") \
    for (int mf = 0; mf < 2; ++mf) _Pragma("unroll") \
    for (int kq = 0; kq < 2; ++kq) \
        af[mf][kq] = *reinterpret_cast<const v8bf*>( \
            qA[(k0_) + kq] + mf * 2048 + (BI) * 8192); }
#define Q_ST(s, bi) do { \
    const int db_ = ((s) >= 4 ? 16384 : 0) + (bi) * 8192 + ((s) & 3) * 2048; \
    gload_lds16(qS[s], lds + db_ + wid * 512); qS[s] += 64; } while (0)
#define Q_TILE(BI, stA_, stB_) do { \
    v8bf af[2][2], bf[2][4]; \
    Q_RA2(af, 0, BI); \
    _Pragma("unroll") for (int cf = 0; cf < 2; ++cf) _Pragma("unroll") \
    for (int kk = 0; kk < 4; ++kk) \
        bf[cf][kk] = *reinterpret_cast<const v8bf*>( \
            qB[kk] + cf * 2048 + (BI) * 8192); \
    if (stA_) { Q_ST(0, (BI) ^ 1); Q_ST(1, (BI) ^ 1); Q_ST(2, (BI) ^ 1); Q_ST(3, (BI) ^ 1); } \
    PRIO1; \
    _Pragma("unroll") for (int mf = 0; mf < 2; ++mf) _Pragma("unroll") \
    for (int cf = 0; cf < 2; ++cf) { \
        MMA32(acc[mf][cf], af[mf][0], bf[cf][0]); \
        MMA32(acc[mf][cf], af[mf][1], bf[cf][1]); } \
    PRIO0; LGKM0(); BARM(); \
    Q_RA2(af, 2, BI); \
    if (stB_) { Q_ST(4, BI); Q_ST(5, BI); Q_ST(6, BI); Q_ST(7, BI); } \
    PRIO1; \
    _Pragma("unroll") for (int mf = 0; mf < 2; ++mf) _Pragma("unroll") \
    for (int cf = 0; cf < 2; ++cf) { \
        MMA32(acc[mf][cf], af[mf][0], bf[cf][2]); \
        MMA32(acc[mf][cf], af[mf][1], bf[cf][3]); } \
    PRIO0; LGKM0(); \
    if (stB_) { VMK(4); } else { VMK(0); } \
    BARM(); } while (0)

template<int EPI, int NBX>
__global__ __launch_bounds__(256, 2) void gemm4p_kernel(
    const u16* __restrict__ A, const u16* __restrict__ Bm, void* __restrict__ Cout,
    const int K, const int NO, const int NT,
    const u16* __restrict__ aux, const float* __restrict__ dskip)
{
    __shared__ u16 lds[32768];
    const int tid = threadIdx.x, lane = tid & 63, wid = tid >> 6;
    const int wm = wid >> 1, wn = wid & 1;
    const int l31 = lane & 31, lh = lane >> 5, l7 = lane & 7;
    const int bid = blockIdx.x;
    const int chunk = (int)gridDim.x >> 3;
    const int swz = (bid & 7) * chunk + (bid >> 3);
    const int by = swz / NBX, bx = swz % NBX;
    const int m0 = by * 128, n0 = bx * 128;

    const int rl = lane >> 3;
    const int scol = ((lane & 7) ^ rl) * 8;
    const u16* qS[8];
    #pragma unroll
    for (int s = 0; s < 4; ++s)
        qS[s] = A + (size_t)(m0 + s * 32 + wid * 8 + rl) * K + scol;
    #pragma unroll
    for (int s = 4; s < 8; ++s)
        qS[s] = Bm + (size_t)(n0 + (s - 4) * 32 + wid * 8 + rl) * K + scol;
    const u16* qA[4];
    const u16* qB[4];
    #pragma unroll
    for (int kk = 0; kk < 4; ++kk) {
        const int phys = ((kk * 2 + lh) ^ l7) * 8;
        qA[kk] = lds + (wm * 64 + l31) * 64 + phys;
        qB[kk] = lds + 16384 + (wn * 64 + l31) * 64 + phys;
    }

    f32x16 acc[2][2] = {};

    #pragma unroll
    for (int t = 0; t < 2; ++t) {
        Q_ST(0, t); Q_ST(1, t); Q_ST(2, t); Q_ST(3, t);
        Q_ST(4, t); Q_ST(5, t); Q_ST(6, t); Q_ST(7, t);
    }
    VMK(0);
    BARM();

    const int NI = NT >> 1;
    for (int i = 0; i < NI; ++i) {
        const bool s1 = (i > 0);
        const bool s2 = (2 * i + 2 < NT);
        const bool s3 = (2 * i + 3 < NT);
        Q_TILE(0, s1, s2);
        Q_TILE(1, s2, s3);
    }

    #pragma unroll
    for (int mf = 0; mf < 2; ++mf)
    #pragma unroll
    for (int cf = 0; cf < 2; ++cf)
    #pragma unroll
    for (int q = 0; q < 16; ++q) {
        const int r = m0 + wm * 64 + mf * 32 + (q & 3) + 8 * (q >> 2) + 4 * lh;
        const int c = n0 + wn * 64 + cf * 32 + l31;
        const size_t o = (size_t)r * NO + c;
        const float v = acc[mf][cf][q];
        if constexpr (EPI == 1) {
            const float u = us2f(aux[o]);
            const float t2 = v + dskip[c] * u;
            ((u16*)Cout)[o] = f2us(gelu_f(t2) + u);
        } else {
            ((float*)Cout)[o] = v + us2f(aux[o]);
        }
    }
}

// ---------- workspace layout (bytes) ----------
static constexpr size_t OFF_FX  = 0;
static constexpr size_t OFF_BU  = 16777216;
static constexpr size_t OFF_A2  = 20971520;
static constexpr size_t OFF_E2  = 0;
static constexpr size_t OFF_FX2 = 33554432;
static constexpr size_t OFF_BB  = 50331648;
static constexpr size_t OFF_C2  = 50593792;
static constexpr size_t OFF_WE  = 50855936;
static constexpr size_t OFF_WD  = 59244544;

extern "C" void kernel_launch(void* const* d_in, const int* in_sizes, int n_in,
                              void* d_out, int out_size, void* d_ws, size_t ws_size,
                              hipStream_t stream) {
    const float* x    = (const float*)d_in[0];
    const float* l1g  = (const float*)d_in[1];
    const float* l1b  = (const float*)d_in[2];
    const float* l2g  = (const float*)d_in[3];
    const float* l2b  = (const float*)d_in[4];
    const float* Lre  = (const float*)d_in[5];
    const float* Lim  = (const float*)d_in[6];
    const float* Bre  = (const float*)d_in[7];
    const float* Bim  = (const float*)d_in[8];
    const float* Cre  = (const float*)d_in[9];
    const float* Cim  = (const float*)d_in[10];
    const float* Dsk  = (const float*)d_in[11];
    const float* lst  = (const float*)d_in[12];
    const float* Wenc = (const float*)d_in[13];
    const float* Wdec = (const float*)d_in[14];
    float* out = (float*)d_out;

    char* ws = (char*)d_ws;
    u16*   fx   = (u16*)(ws + OFF_FX);
    float* Bu   = (float*)(ws + OFF_BU);
    u16*   A2   = (u16*)(ws + OFF_A2);
    u16*   e2   = (u16*)(ws + OFF_E2);
    u16*   fx2  = (u16*)(ws + OFF_FX2);
    u16*   Bbar = (u16*)(ws + OFF_BB);
    u16*   C2   = (u16*)(ws + OFF_C2);
    u16*   WeB  = (u16*)(ws + OFF_WE);
    u16*   WdB  = (u16*)(ws + OFF_WD);
    u16*   h    = (u16*)d_out;           // h (bf16) in d_out's first half

    // 1) fx = LN1(x)
    ln_kernel<float><<<8192, 256, 0, stream>>>(x, l1g, l1b, fx);
    // 1b) weight conversions + B_bar / C2 precompute (fused)
    prepall_kernel<<<3584, 256, 0, stream>>>(Wenc, WeB, Wdec, WdB,
                                             Lre, Lim, lst, Bre, Bim, Cre, Cim,
                                             Bbar, C2);
    // 2) Bu = fx @ Bbar^T
    gemm_small_kernel<64, 64><<<dim3(2, 128), 64, 0, stream>>>(
        fx, Bbar, Bu, 128, 1024);
    // 3) scan -> A2
    scan_kernel<<<256, 256, 0, stream>>>(Bu, Lre, Lim, lst, A2);
    // 4) h = gelu(A2 @ C2^T + Dskip*fx) + fx   (128x128 tiles, NT=2)
    gemm4p_kernel<1, 8><<<512, 256, 0, stream>>>(
        A2, C2, h, 128, 1024, 2, fx, Dsk);
    // 5) fx2 = LN2(h)
    ln_kernel<u16><<<8192, 256, 0, stream>>>(h, l2g, l2b, fx2);
    // 6) e2 = (fx2 @ We[:2048]^T) * gelu(fx2 @ We[2048:]^T)
    geglu_kernel<16><<<512, 512, 0, stream>>>(fx2, WeB, e2, 1024, 2048, 16);
    // 7) out = e2 @ WdB^T + fx2
    gemm4p_kernel<3, 8><<<512, 256, 0, stream>>>(
        e2, WdB, out, 2048, 1024, 32, fx2, nullptr);

    (void)in_sizes; (void)n_in; (void)out_size; (void)ws_size;
}

// Round 11
// 221.530 us; speedup vs baseline: 1.0402x; 1.0082x over previous
//
#include <hip/hip_runtime.h>
#include <hip/hip_bf16.h>
#include <math.h>

typedef unsigned short u16;
typedef __bf16 v8bf __attribute__((ext_vector_type(8)));
typedef float f32x4 __attribute__((ext_vector_type(4)));
typedef float f32x16 __attribute__((ext_vector_type(16)));

// ---------- bf16 helpers ----------
__device__ __forceinline__ float us2f(u16 h) {
    union { unsigned int u; float f; } v; v.u = ((unsigned int)h) << 16; return v.f;
}
__device__ __forceinline__ u16 f2us(float f) {
    union { float f; unsigned int u; } v; v.f = f;
    unsigned int r = v.u + 0x7fffu + ((v.u >> 16) & 1u);   // RNE
    return (u16)(r >> 16);
}
__device__ __forceinline__ float gelu_f(float x) {
    return 0.5f * x * (1.0f + erff(x * 0.70710678118654752f));
}
__device__ __forceinline__ void gload_lds16(const u16* g, u16* l) {
    auto gp = reinterpret_cast<const __attribute__((address_space(1))) unsigned int*>(
        (uintptr_t)g);
    auto lp = reinterpret_cast<__attribute__((address_space(3))) unsigned int*>(
        (uintptr_t)l);
    __builtin_amdgcn_global_load_lds(gp, lp, 16, 0, 0);
}

// ---------- fused pre: LN1 + cvt Wenc/Wdec + Bbar/C2 ----------
__global__ __launch_bounds__(256) void pre_kernel(
    const float* __restrict__ x, const float* __restrict__ l1g,
    const float* __restrict__ l1b, u16* __restrict__ fx,
    const float* __restrict__ Wenc, u16* __restrict__ WeB,
    const float* __restrict__ Wdec, u16* __restrict__ WdB,
    const float* __restrict__ Lre, const float* __restrict__ Lim,
    const float* __restrict__ lstep,
    const float* __restrict__ Bre, const float* __restrict__ Bim,
    const float* __restrict__ Cre, const float* __restrict__ Cim,
    u16* __restrict__ Bbar, u16* __restrict__ C2)
{
    const int blk = blockIdx.x, tid = threadIdx.x;
    if (blk < 8192) {
        // ---- LN1 row blk ----
        const size_t base = (size_t)blk * 1024 + tid * 4;
        float4 v = *reinterpret_cast<const float4*>(x + base);
        float x0 = v.x, x1 = v.y, x2 = v.z, x3 = v.w;
        float s = x0 + x1 + x2 + x3;
        float q = x0*x0 + x1*x1 + x2*x2 + x3*x3;
        #pragma unroll
        for (int o = 32; o; o >>= 1) { s += __shfl_down(s, o); q += __shfl_down(q, o); }
        __shared__ float red[8];
        if ((tid & 63) == 0) { red[tid >> 6] = s; red[4 + (tid >> 6)] = q; }
        __syncthreads();
        s = red[0] + red[1] + red[2] + red[3];
        q = red[4] + red[5] + red[6] + red[7];
        const float mu = s * (1.0f / 1024.0f);
        const float rs = rsqrtf(q * (1.0f / 1024.0f) - mu * mu + 1e-5f);
        float4 gv = *reinterpret_cast<const float4*>(l1g + tid * 4);
        float4 bv = *reinterpret_cast<const float4*>(l1b + tid * 4);
        ushort4 o4;
        o4.x = f2us((x0 - mu) * rs * gv.x + bv.x);
        o4.y = f2us((x1 - mu) * rs * gv.y + bv.y);
        o4.z = f2us((x2 - mu) * rs * gv.z + bv.z);
        o4.w = f2us((x3 - mu) * rs * gv.w + bv.w);
        *reinterpret_cast<ushort4*>(fx + base) = o4;
        return;
    }
    const int b = blk - 8192;
    if (b < 3072) {
        const float* in = (b < 2048) ? Wenc : Wdec;
        u16* outp = (b < 2048) ? WeB : WdB;
        const int i = (b < 2048 ? b : b - 2048) * 2048 + tid * 8;
        float4 a = *reinterpret_cast<const float4*>(in + i);
        float4 c = *reinterpret_cast<const float4*>(in + i + 4);
        u16 o[8] = { f2us(a.x), f2us(a.y), f2us(a.z), f2us(a.w),
                     f2us(c.x), f2us(c.y), f2us(c.z), f2us(c.w) };
        *reinterpret_cast<uint4*>(outp + i) = *reinterpret_cast<uint4*>(o);
        return;
    }
    const int idx = (b - 3072) * 256 + tid;
    if (idx < 65536) {
        const int p = idx >> 10, d = idx & 1023;
        const float lr = Lre[p], li = Lim[p];
        const float dt = expf(lstep[p]);
        const float er = expf(lr * dt);
        const float ar = er * cosf(li * dt), ai = er * sinf(li * dt);
        const float nr = ar - 1.0f, ni = ai;
        const float den = lr * lr + li * li;
        const float cr = (nr * lr + ni * li) / den;
        const float ci = (ni * lr - nr * li) / den;
        const float br = Bre[idx], bi = Bim[idx];
        Bbar[p * 1024 + d]        = f2us(cr * br - ci * bi);
        Bbar[(64 + p) * 1024 + d] = f2us(cr * bi + ci * br);
    } else {
        const int i = idx - 65536;
        const int d = i >> 6, p = i & 63;
        C2[d * 128 + p]      = f2us( 2.0f * Cre[i]);
        C2[d * 128 + 64 + p] = f2us(-2.0f * Cim[i]);
    }
}

// ---------- LayerNorm (bf16 input; used for LN2) ----------
template<typename TIN>
__global__ __launch_bounds__(256) void ln_kernel(const TIN* __restrict__ in,
                                                 const float* __restrict__ g,
                                                 const float* __restrict__ b,
                                                 u16* __restrict__ out)
{
    const int row = blockIdx.x, tid = threadIdx.x;
    const size_t base = (size_t)row * 1024 + tid * 4;
    float x0, x1, x2, x3;
    if constexpr (sizeof(TIN) == 4) {
        float4 v = *reinterpret_cast<const float4*>(in + base);
        x0 = v.x; x1 = v.y; x2 = v.z; x3 = v.w;
    } else {
        ushort4 v = *reinterpret_cast<const ushort4*>((const u16*)in + base);
        x0 = us2f(v.x); x1 = us2f(v.y); x2 = us2f(v.z); x3 = us2f(v.w);
    }
    float s = x0 + x1 + x2 + x3;
    float q = x0*x0 + x1*x1 + x2*x2 + x3*x3;
    #pragma unroll
    for (int o = 32; o; o >>= 1) { s += __shfl_down(s, o); q += __shfl_down(q, o); }
    __shared__ float red[8];
    if ((tid & 63) == 0) { red[tid >> 6] = s; red[4 + (tid >> 6)] = q; }
    __syncthreads();
    s = red[0] + red[1] + red[2] + red[3];
    q = red[4] + red[5] + red[6] + red[7];
    const float mu = s * (1.0f / 1024.0f);
    const float rs = rsqrtf(q * (1.0f / 1024.0f) - mu * mu + 1e-5f);
    float4 gv = *reinterpret_cast<const float4*>(g + tid * 4);
    float4 bv = *reinterpret_cast<const float4*>(b + tid * 4);
    ushort4 o4;
    o4.x = f2us((x0 - mu) * rs * gv.x + bv.x);
    o4.y = f2us((x1 - mu) * rs * gv.y + bv.y);
    o4.z = f2us((x2 - mu) * rs * gv.z + bv.z);
    o4.w = f2us((x3 - mu) * rs * gv.w + bv.w);
    *reinterpret_cast<ushort4*>(out + base) = o4;
}

// ---------- scan ----------
__global__ __launch_bounds__(256) void scan_kernel(
    const float* __restrict__ Bu,
    const float* __restrict__ Lre, const float* __restrict__ Lim,
    const float* __restrict__ lstep,
    u16* __restrict__ A2)
{
    const int b = blockIdx.x >> 6;
    const int p = blockIdx.x & 63;
    const int t = threadIdx.x;
    const float lr = Lre[p], li = Lim[p];
    const float dt = expf(lstep[p]);
    const float er = expf(lr * dt);
    const float ar = er * cosf(li * dt), ai = er * sinf(li * dt);

    const size_t base = ((size_t)b * 2048 + t * 8) * 128;
    float xr[8], xi[8];
    float sr = 0.f, si = 0.f;
    #pragma unroll
    for (int i = 0; i < 8; ++i) {
        const float br = Bu[base + i * 128 + p];
        const float bi = Bu[base + i * 128 + 64 + p];
        const float nr = ar * sr - ai * si + br;
        const float ni = ar * si + ai * sr + bi;
        sr = nr; si = ni;
        xr[i] = sr; xi[i] = si;
    }
    float fr = ar, fi = ai;
    #pragma unroll
    for (int s = 0; s < 3; ++s) { const float t2 = fr*fr - fi*fi; fi = 2.f*fr*fi; fr = t2; }
    __shared__ float Er[256], Ei[256];
    Er[t] = sr; Ei[t] = si;
    __syncthreads();
    float vr = sr, vi = si;
    for (int off = 1; off < 256; off <<= 1) {
        float pr = 0.f, pi = 0.f;
        if (t >= off) { pr = Er[t - off]; pi = Ei[t - off]; }
        __syncthreads();
        vr += fr * pr - fi * pi;
        vi += fr * pi + fi * pr;
        Er[t] = vr; Ei[t] = vi;
        const float nf = fr*fr - fi*fi; fi = 2.f*fr*fi; fr = nf;
        __syncthreads();
    }
    float cr = 0.f, ci = 0.f;
    if (t > 0) { cr = Er[t - 1]; ci = Ei[t - 1]; }
    float gr = ar * cr - ai * ci, gi = ar * ci + ai * cr;
    #pragma unroll
    for (int i = 0; i < 8; ++i) {
        xr[i] += gr; xi[i] += gi;
        const float n2 = ar * gr - ai * gi; gi = ar * gi + ai * gr; gr = n2;
    }
    #pragma unroll
    for (int i = 0; i < 8; ++i) {
        const size_t m = (size_t)b * 2048 + t * 8 + i;
        A2[m * 128 + p]      = f2us(xr[i]);
        A2[m * 128 + 64 + p] = f2us(xi[i]);
    }
}

// ---------- small MFMA GEMM (G1 Bu) ----------
template<int BM, int BN>
__global__ __launch_bounds__(64) void gemm_small_kernel(
    const u16* __restrict__ A, const u16* __restrict__ B, float* __restrict__ Cout,
    const int N, const int K)
{
    __shared__ u16 lsA[BM * 32];
    __shared__ u16 lsB[BN * 32];
    const int tid = threadIdx.x;
    const int lane = tid & 63;
    const int m0 = blockIdx.y * BM, n0 = blockIdx.x * BN;
    f32x4 acc[4][4] = {};
    for (int k0 = 0; k0 < K; k0 += 32) {
        #pragma unroll
        for (int j = 0; j < 4; ++j) {
            const int s = j * 64 + tid;
            gload_lds16(A + (size_t)(m0 + (s >> 2)) * K + k0 + (s & 3) * 8,
                        lsA + (s - lane) * 8);
            gload_lds16(B + (size_t)(n0 + (s >> 2)) * K + k0 + (s & 3) * 8,
                        lsB + (s - lane) * 8);
        }
        __syncthreads();
        v8bf af[4], bfv[4];
        #pragma unroll
        for (int f = 0; f < 4; ++f)
            af[f] = *reinterpret_cast<const v8bf*>(
                lsA + (f * 16 + (lane & 15)) * 32 + (lane >> 4) * 8);
        #pragma unroll
        for (int f = 0; f < 4; ++f)
            bfv[f] = *reinterpret_cast<const v8bf*>(
                lsB + (f * 16 + (lane & 15)) * 32 + (lane >> 4) * 8);
        #pragma unroll
        for (int fm = 0; fm < 4; ++fm)
            #pragma unroll
            for (int fn = 0; fn < 4; ++fn)
                acc[fm][fn] = __builtin_amdgcn_mfma_f32_16x16x32_bf16(
                    af[fm], bfv[fn], acc[fm][fn], 0, 0, 0);
        __syncthreads();
    }
    #pragma unroll
    for (int fm = 0; fm < 4; ++fm)
    #pragma unroll
    for (int fn = 0; fn < 4; ++fn)
    #pragma unroll
    for (int i = 0; i < 4; ++i) {
        const int r = m0 + fm * 16 + (lane >> 4) * 4 + i;
        const int c = n0 + fn * 16 + (lane & 15);
        Cout[(size_t)r * N + c] = acc[fm][fn][i];
    }
}

// ================= pipelined GEMMs =================
#define BARM()   asm volatile("s_barrier" ::: "memory")
#define LGKM0()  asm volatile("s_waitcnt lgkmcnt(0)" ::: "memory")
#define VMK(n)   asm volatile("s_waitcnt vmcnt(" #n ")" ::: "memory")
#define PRIO1    __builtin_amdgcn_s_setprio(1)
#define PRIO0    __builtin_amdgcn_s_setprio(0)
#define MMA32(acc, a, b) \
    acc = __builtin_amdgcn_mfma_f32_32x32x16_bf16(a, b, acc, 0, 0, 0)

// ---------------- GEGLU: 256x128 tile, BK=64, 8 waves, LDS 160KB ----------------
// A TRIPLE-buffered (2-tile lookahead), B double-buffered.
// LDS u16: Abuf0 [0,16384) | Abuf1 [16384,32768) | Abuf2 [32768,49152)
//        | Bbuf0 [49152,65536) | Bbuf1 [65536,81920). B rows: 0-127 a, 128-255 gate.
// Ledger: prologue issues A0,B0,A1,B1 (16 gloads) -> VMK(8) (A0,B0 landed).
// Tile t: ph0-1 stage A(t+2)->Abuf[(t+2)%3]; ph2-3 stage B(t+2)->Bbuf[t&1];
// end VMK(8) -> A(t+1),B(t+1) (issued in tile t-1, age=1 full tile) landed.
#define G_RA(af, kk, AI) { _Pragma("unroll") \
    for (int mf = 0; mf < 4; ++mf) \
        af[mf] = *reinterpret_cast<const v8bf*>( \
            pA[kk] + (AI) * 16384 + mf * 2048); }
#define G_RB(kk, ag, BI) \
    (*reinterpret_cast<const v8bf*>(pB[kk] + (BI) * 16384 + (ag) * 8192))
#define G_STA(s, ai) do { \
    gload_lds16(pS[s][0], lds + (ai) * 16384 + (s) * 8192 + (wid * 2 + 0) * 512); \
    gload_lds16(pS[s][1], lds + (ai) * 16384 + (s) * 8192 + (wid * 2 + 1) * 512); \
    pS[s][0] += 64; pS[s][1] += 64; } while (0)
#define G_STB(s, bi) do { \
    gload_lds16(pS[s][0], lds + 49152 + (bi) * 16384 + ((s) - 2) * 8192 + (wid * 2 + 0) * 512); \
    gload_lds16(pS[s][1], lds + 49152 + (bi) * 16384 + ((s) - 2) * 8192 + (wid * 2 + 1) * 512); \
    pS[s][0] += 64; pS[s][1] += 64; } while (0)
#define G_MM(kk) { _Pragma("unroll") \
    for (int mf = 0; mf < 4; ++mf) { \
        MMA32(accA[mf], af[mf], bA[kk]); MMA32(accG[mf], af[mf], bG[kk]); } }

template<int NBX, int NT>
__global__ __launch_bounds__(512, 2) void geglu_kernel(
    const u16* __restrict__ A, const u16* __restrict__ Bm, u16* __restrict__ Cout,
    const int K, const int NO)
{
    __shared__ u16 lds[81920];   // 160 KiB exactly
    const int tid = threadIdx.x, lane = tid & 63, wid = tid >> 6;
    const int wm = wid >> 2, wn = wid & 3;
    const int l31 = lane & 31, lh = lane >> 5, l7 = lane & 7;
    const int bid = blockIdx.x;
    const int chunk = (int)gridDim.x >> 3;
    const int swz = (bid & 7) * chunk + (bid >> 3);
    const int by = swz / NBX, bx = swz % NBX;
    const int m0 = by * 256, n0 = bx * 128;

    const int rl = lane >> 3;
    const int scol = ((lane & 7) ^ rl) * 8;
    const u16* pS[4][2];
    #pragma unroll
    for (int j = 0; j < 2; ++j) {
        const int rloc = (wid * 2 + j) * 8 + rl;
        pS[0][j] = A  + (size_t)(m0 + rloc)       * K + scol;
        pS[1][j] = A  + (size_t)(m0 + 128 + rloc) * K + scol;
        pS[2][j] = Bm + (size_t)(n0 + rloc)       * K + scol;
        pS[3][j] = Bm + (size_t)(NO + n0 + rloc)  * K + scol;
    }
    const u16* pA[4];
    const u16* pB[4];
    #pragma unroll
    for (int kk = 0; kk < 4; ++kk) {
        const int phys = ((kk * 2 + lh) ^ l7) * 8;
        pA[kk] = lds + (wm * 128 + l31) * 64 + phys;
        pB[kk] = lds + 49152 + (wn * 32 + l31) * 64 + phys;
    }

    f32x16 accA[4] = {};
    f32x16 accG[4] = {};

    // prologue: A0,B0,A1,B1 (issue order matters for the FIFO vmcnt ledger)
    G_STA(0, 0); G_STA(1, 0);
    G_STB(2, 0); G_STB(3, 0);
    G_STA(0, 1); G_STA(1, 1);
    G_STB(2, 1); G_STB(3, 1);
    VMK(8);
    BARM();

    #pragma unroll
    for (int t = 0; t < NT; ++t) {
        const int AI = t % 3, AN = (t + 2) % 3, BI = t & 1;
        const bool st = (t + 2 < NT);
        v8bf af[4], bA[4], bG[4];
        // ph0: A kk0 + ALL B reads (B region re-staged ph2-3; reads drain here)
        G_RA(af, 0, AI);
        #pragma unroll
        for (int kk = 0; kk < 4; ++kk) {
            bA[kk] = G_RB(kk, 0, BI); bG[kk] = G_RB(kk, 1, BI);
        }
        if (st) G_STA(0, AN);
        PRIO1; G_MM(0); PRIO0; LGKM0(); BARM();
        // ph1
        G_RA(af, 1, AI);
        if (st) G_STA(1, AN);
        PRIO1; G_MM(1); PRIO0; LGKM0(); BARM();
        // ph2
        G_RA(af, 2, AI);
        if (st) G_STB(2, BI);
        PRIO1; G_MM(2); PRIO0; LGKM0(); BARM();
        // ph3
        G_RA(af, 3, AI);
        if (st) G_STB(3, BI);
        PRIO1; G_MM(3); PRIO0; LGKM0();
        if (st) { VMK(8); } else { VMK(0); }
        BARM();
    }

    #pragma unroll
    for (int mf = 0; mf < 4; ++mf)
    #pragma unroll
    for (int q = 0; q < 16; ++q) {
        const int r = m0 + wm * 128 + mf * 32 + (q & 3) + 8 * (q >> 2) + 4 * lh;
        const int c = n0 + wn * 32 + l31;
        Cout[(size_t)r * NO + c] = f2us(accA[mf][q] * gelu_f(accG[mf][q]));
    }
}

// ---------------- plain GEMM: 128x128 tile, BK=64, 4 waves, LDS 64KB ----------------
// (round-10 proven; unchanged)
#define Q_RA2(af, k0_, BI) { _Pragma("unroll") \
    for (int mf = 0; mf < 2; ++mf) _Pragma("unroll") \
    for (int kq = 0; kq < 2; ++kq) \
        af[mf][kq] = *reinterpret_cast<const v8bf*>( \
            qA[(k0_) + kq] + mf * 2048 + (BI) * 8192); }
#define Q_ST(s, bi) do { \
    const int db_ = ((s) >= 4 ? 16384 : 0) + (bi) * 8192 + ((s) & 3) * 2048; \
    gload_lds16(qS[s], lds + db_ + wid * 512); qS[s] += 64; } while (0)
#define Q_TILE(BI, stA_, stB_) do { \
    v8bf af[2][2], bf[2][4]; \
    Q_RA2(af, 0, BI); \
    _Pragma("unroll") for (int cf = 0; cf < 2; ++cf) _Pragma("unroll") \
    for (int kk = 0; kk < 4; ++kk) \
        bf[cf][kk] = *reinterpret_cast<const v8bf*>( \
            qB[kk] + cf * 2048 + (BI) * 8192); \
    if (stA_) { Q_ST(0, (BI) ^ 1); Q_ST(1, (BI) ^ 1); Q_ST(2, (BI) ^ 1); Q_ST(3, (BI) ^ 1); } \
    PRIO1; \
    _Pragma("unroll") for (int mf = 0; mf < 2; ++mf) _Pragma("unroll") \
    for (int cf = 0; cf < 2; ++cf) { \
        MMA32(acc[mf][cf], af[mf][0], bf[cf][0]); \
        MMA32(acc[mf][cf], af[mf][1], bf[cf][1]); } \
    PRIO0; LGKM0(); BARM(); \
    Q_RA2(af, 2, BI); \
    if (stB_) { Q_ST(4, BI); Q_ST(5, BI); Q_ST(6, BI); Q_ST(7, BI); } \
    PRIO1; \
    _Pragma("unroll") for (int mf = 0; mf < 2; ++mf) _Pragma("unroll") \
    for (int cf = 0; cf < 2; ++cf) { \
        MMA32(acc[mf][cf], af[mf][0], bf[cf][2]); \
        MMA32(acc[mf][cf], af[mf][1], bf[cf][3]); } \
    PRIO0; LGKM0(); \
    if (stB_) { VMK(4); } else { VMK(0); } \
    BARM(); } while (0)

template<int EPI, int NBX>
__global__ __launch_bounds__(256, 2) void gemm4p_kernel(
    const u16* __restrict__ A, const u16* __restrict__ Bm, void* __restrict__ Cout,
    const int K, const int NO, const int NT,
    const u16* __restrict__ aux, const float* __restrict__ dskip)
{
    __shared__ u16 lds[32768];
    const int tid = threadIdx.x, lane = tid & 63, wid = tid >> 6;
    const int wm = wid >> 1, wn = wid & 1;
    const int l31 = lane & 31, lh = lane >> 5, l7 = lane & 7;
    const int bid = blockIdx.x;
    const int chunk = (int)gridDim.x >> 3;
    const int swz = (bid & 7) * chunk + (bid >> 3);
    const int by = swz / NBX, bx = swz % NBX;
    const int m0 = by * 128, n0 = bx * 128;

    const int rl = lane >> 3;
    const int scol = ((lane & 7) ^ rl) * 8;
    const u16* qS[8];
    #pragma unroll
    for (int s = 0; s < 4; ++s)
        qS[s] = A + (size_t)(m0 + s * 32 + wid * 8 + rl) * K + scol;
    #pragma unroll
    for (int s = 4; s < 8; ++s)
        qS[s] = Bm + (size_t)(n0 + (s - 4) * 32 + wid * 8 + rl) * K + scol;
    const u16* qA[4];
    const u16* qB[4];
    #pragma unroll
    for (int kk = 0; kk < 4; ++kk) {
        const int phys = ((kk * 2 + lh) ^ l7) * 8;
        qA[kk] = lds + (wm * 64 + l31) * 64 + phys;
        qB[kk] = lds + 16384 + (wn * 64 + l31) * 64 + phys;
    }

    f32x16 acc[2][2] = {};

    #pragma unroll
    for (int t = 0; t < 2; ++t) {
        Q_ST(0, t); Q_ST(1, t); Q_ST(2, t); Q_ST(3, t);
        Q_ST(4, t); Q_ST(5, t); Q_ST(6, t); Q_ST(7, t);
    }
    VMK(0);
    BARM();

    const int NI = NT >> 1;
    for (int i = 0; i < NI; ++i) {
        const bool s1 = (i > 0);
        const bool s2 = (2 * i + 2 < NT);
        const bool s3 = (2 * i + 3 < NT);
        Q_TILE(0, s1, s2);
        Q_TILE(1, s2, s3);
    }

    #pragma unroll
    for (int mf = 0; mf < 2; ++mf)
    #pragma unroll
    for (int cf = 0; cf < 2; ++cf)
    #pragma unroll
    for (int q = 0; q < 16; ++q) {
        const int r = m0 + wm * 64 + mf * 32 + (q & 3) + 8 * (q >> 2) + 4 * lh;
        const int c = n0 + wn * 64 + cf * 32 + l31;
        const size_t o = (size_t)r * NO + c;
        const float v = acc[mf][cf][q];
        if constexpr (EPI == 1) {
            const float u = us2f(aux[o]);
            const float t2 = v + dskip[c] * u;
            ((u16*)Cout)[o] = f2us(gelu_f(t2) + u);
        } else {
            ((float*)Cout)[o] = v + us2f(aux[o]);
        }
    }
}

// ---------- workspace layout (bytes) ----------
static constexpr size_t OFF_FX  = 0;
static constexpr size_t OFF_BU  = 16777216;
static constexpr size_t OFF_A2  = 20971520;
static constexpr size_t OFF_E2  = 0;
static constexpr size_t OFF_FX2 = 33554432;
static constexpr size_t OFF_BB  = 50331648;
static constexpr size_t OFF_C2  = 50593792;
static constexpr size_t OFF_WE  = 50855936;
static constexpr size_t OFF_WD  = 59244544;

extern "C" void kernel_launch(void* const* d_in, const int* in_sizes, int n_in,
                              void* d_out, int out_size, void* d_ws, size_t ws_size,
                              hipStream_t stream) {
    const float* x    = (const float*)d_in[0];
    const float* l1g  = (const float*)d_in[1];
    const float* l1b  = (const float*)d_in[2];
    const float* l2g  = (const float*)d_in[3];
    const float* l2b  = (const float*)d_in[4];
    const float* Lre  = (const float*)d_in[5];
    const float* Lim  = (const float*)d_in[6];
    const float* Bre  = (const float*)d_in[7];
    const float* Bim  = (const float*)d_in[8];
    const float* Cre  = (const float*)d_in[9];
    const float* Cim  = (const float*)d_in[10];
    const float* Dsk  = (const float*)d_in[11];
    const float* lst  = (const float*)d_in[12];
    const float* Wenc = (const float*)d_in[13];
    const float* Wdec = (const float*)d_in[14];
    float* out = (float*)d_out;

    char* ws = (char*)d_ws;
    u16*   fx   = (u16*)(ws + OFF_FX);
    float* Bu   = (float*)(ws + OFF_BU);
    u16*   A2   = (u16*)(ws + OFF_A2);
    u16*   e2   = (u16*)(ws + OFF_E2);
    u16*   fx2  = (u16*)(ws + OFF_FX2);
    u16*   Bbar = (u16*)(ws + OFF_BB);
    u16*   C2   = (u16*)(ws + OFF_C2);
    u16*   WeB  = (u16*)(ws + OFF_WE);
    u16*   WdB  = (u16*)(ws + OFF_WD);
    u16*   h    = (u16*)d_out;           // h (bf16) in d_out's first half

    // 1) fused: LN1 + weight cvts + Bbar/C2
    pre_kernel<<<11776, 256, 0, stream>>>(x, l1g, l1b, fx,
                                          Wenc, WeB, Wdec, WdB,
                                          Lre, Lim, lst, Bre, Bim, Cre, Cim,
                                          Bbar, C2);
    // 2) Bu = fx @ Bbar^T
    gemm_small_kernel<64, 64><<<dim3(2, 128), 64, 0, stream>>>(
        fx, Bbar, Bu, 128, 1024);
    // 3) scan -> A2
    scan_kernel<<<256, 256, 0, stream>>>(Bu, Lre, Lim, lst, A2);
    // 4) h = gelu(A2 @ C2^T + Dskip*fx) + fx
    gemm4p_kernel<1, 8><<<512, 256, 0, stream>>>(
        A2, C2, h, 128, 1024, 2, fx, Dsk);
    // 5) fx2 = LN2(h)
    ln_kernel<u16><<<8192, 256, 0, stream>>>(h, l2g, l2b, fx2);
    // 6) e2 = (fx2 @ We[:2048]^T) * gelu(fx2 @ We[2048:]^T)   [A-triple-buffer]
    geglu_kernel<16, 16><<<512, 512, 0, stream>>>(fx2, WeB, e2, 1024, 2048);
    // 7) out = e2 @ WdB^T + fx2
    gemm4p_kernel<3, 8><<<512, 256, 0, stream>>>(
        e2, WdB, out, 2048, 1024, 32, fx2, nullptr);

    (void)in_sizes; (void)n_in; (void)out_size; (void)ws_size;
}